// Round 1
// baseline (211.323 us; speedup 1.0000x reference)
//
#include <hip/hip_runtime.h>

// EdgeConv, algebraically simplified:
//   out[p,o] = sum_c (t[p,c]/K - x[p,c])*W[o,c] + sum_c x[p,c]*W[o,64+c] + bias[o]
//   t[p,c]   = sum_{k=0..19} g_flat[p, 20c+k],  g_flat[p,j] = x[b, adj[p, j>>6], j&63]
// (the reference's raw (K,C)->(C,K) reshape makes the einsum collapse into
//  aligned 20-wide window sums over the flat gather buffer)

namespace {
constexpr int B_    = 4;
constexpr int N_    = 32768;
constexpr int K_    = 20;
constexpr int C_    = 64;
constexpr int O_    = 64;
constexpr int PTOT  = B_ * N_;       // 131072 points
constexpr int BLOCK = 256;           // 4 waves
constexpr int WPB   = 4;             // waves per block
constexpr int GRID  = 1024;          // 4096 waves -> 32 points/wave
constexpr int WROW  = 132;           // padded W row stride in LDS (floats)
}

__global__ __launch_bounds__(BLOCK) void edgeconv_kernel(
    const float* __restrict__ x,     // (B,N,C)
    const int*   __restrict__ adj,   // (B,N,K)
    const float* __restrict__ W,     // (O, 2C)
    const float* __restrict__ bias,  // (O,)
    float*       __restrict__ out)   // (B,N,O)
{
  __shared__ __align__(16) float wstage[O_ * WROW];      // 33 KB, used once
  __shared__ __align__(16) float win[WPB][K_ * C_];      // 4 * 5120 B
  __shared__ __align__(16) float buf[WPB][2 * C_];       // 4 * 512 B

  const int lane = threadIdx.x & 63;
  const int wid  = __builtin_amdgcn_readfirstlane((int)(threadIdx.x >> 6));

  // ---- stage W into LDS (coalesced), then each lane pulls its row into VGPRs
  for (int i = threadIdx.x; i < O_ * 2 * C_; i += BLOCK) {
    const int r = i >> 7;          // / 128
    const int c = i & 127;
    wstage[r * WROW + c] = W[i];
  }
  __syncthreads();

  float4 w4[32];                   // lane o holds W[o][0..127]
  {
    const float4* wrow = reinterpret_cast<const float4*>(wstage + lane * WROW);
#pragma unroll
    for (int i = 0; i < 32; ++i) w4[i] = wrow[i];
  }
  const float bl = bias[lane];

  float* mywin = win[wid];
  float* mybuf = buf[wid];

  for (int p = blockIdx.x * WPB + wid; p < PTOT; p += GRID * WPB) {
    const int b = p >> 15;                       // p / N
    const float* xb   = x + (size_t)b * N_ * C_;
    const int*   arow = adj + (size_t)p * K_;    // uniform -> s_loads

    // gather: 20 coalesced 256B row loads, lane = channel
    float vals[K_];
#pragma unroll
    for (int k = 0; k < K_; ++k) {
      const int idx = arow[k];                   // SGPR
      vals[k] = xb[idx * C_ + lane];
    }
    const float xv = x[(size_t)p * C_ + lane];

#pragma unroll
    for (int k = 0; k < K_; ++k)
      mywin[k * C_ + lane] = vals[k];            // conflict-free writes
    __syncthreads();

    // window sum: lane c reads flat[20c .. 20c+19] as 5x float4 (80B, 16B-aligned)
    const float4* wp = reinterpret_cast<const float4*>(mywin + lane * K_);
    float t = 0.f;
#pragma unroll
    for (int s = 0; s < 5; ++s) {
      const float4 v = wp[s];
      t += (v.x + v.y) + (v.z + v.w);
    }

    mybuf[lane]      = t * (1.f / K_) - xv;      // a[c]
    mybuf[C_ + lane] = xv;                       // x[c]
    __syncthreads();

    // matvec: out[o] = sum_j buf[j] * W[o][j]  (j = 0..127), W in registers
    float acc0 = 0.f, acc1 = 0.f, acc2 = 0.f, acc3 = 0.f;
    const float4* bp = reinterpret_cast<const float4*>(mybuf);
#pragma unroll
    for (int i = 0; i < 32; i += 4) {
      const float4 v0 = bp[i + 0], v1 = bp[i + 1], v2 = bp[i + 2], v3 = bp[i + 3];
      const float4 u0 = w4[i + 0], u1 = w4[i + 1], u2 = w4[i + 2], u3 = w4[i + 3];
      acc0 = fmaf(v0.w, u0.w, fmaf(v0.z, u0.z, fmaf(v0.y, u0.y, fmaf(v0.x, u0.x, acc0))));
      acc1 = fmaf(v1.w, u1.w, fmaf(v1.z, u1.z, fmaf(v1.y, u1.y, fmaf(v1.x, u1.x, acc1))));
      acc2 = fmaf(v2.w, u2.w, fmaf(v2.z, u2.z, fmaf(v2.y, u2.y, fmaf(v2.x, u2.x, acc2))));
      acc3 = fmaf(v3.w, u3.w, fmaf(v3.z, u3.z, fmaf(v3.y, u3.y, fmaf(v3.x, u3.x, acc3))));
    }

    out[(size_t)p * O_ + lane] = ((acc0 + acc1) + (acc2 + acc3)) + bl;
  }
}

extern "C" void kernel_launch(void* const* d_in, const int* in_sizes, int n_in,
                              void* d_out, int out_size, void* d_ws, size_t ws_size,
                              hipStream_t stream) {
  const float* x    = (const float*)d_in[0];
  const int*   adj  = (const int*)d_in[1];
  const float* W    = (const float*)d_in[2];
  const float* bias = (const float*)d_in[3];
  float* out = (float*)d_out;

  hipLaunchKernelGGL(edgeconv_kernel, dim3(GRID), dim3(BLOCK), 0, stream,
                     x, adj, W, bias, out);
}